// Round 1
// baseline (1718.885 us; speedup 1.0000x reference)
//
#include <hip/hip_runtime.h>
#include <hip/hip_bf16.h>

// Problem constants (shapes fixed by reference; N,E derived from in_sizes)
#define IN_C   128
#define HID    16
#define OUT_C  8
#define EDGE_C 16
#define NG     64

// ---------------------------------------------------------------------------
// deg[v] += 1 for each edge with dst==v  (self-loop +1 folded into dinv)
__global__ void deg_kernel(const int* __restrict__ dst, float* __restrict__ deg, int E) {
    int e = blockIdx.x * blockDim.x + threadIdx.x;
    if (e < E) atomicAdd(&deg[dst[e]], 1.0f);
}

// dinv[v] = rsqrt(deg[v] + 1)   (+1 = self loop; deg>=1 always)
__global__ void dinv_kernel(const float* __restrict__ deg, float* __restrict__ dinv, int n) {
    int v = blockIdx.x * blockDim.x + threadIdx.x;
    if (v < n) dinv[v] = rsqrtf(deg[v] + 1.0f);
}

// a1[v][c] = dinv[v] * sum_k x[v][k] * W[k][c]    (IN_C=128 -> HID=16)
// block=256 threads = 16 nodes x 16 channels
__global__ void xform1_kernel(const float* __restrict__ x, const float* __restrict__ W,
                              const float* __restrict__ dinv, float* __restrict__ a1, int n) {
    int t = threadIdx.x;
    int v = blockIdx.x * 16 + (t >> 4);
    int c = t & 15;
    if (v >= n) return;
    const float4* xr = (const float4*)(x + (size_t)v * IN_C);
    float acc = 0.0f;
#pragma unroll
    for (int k4 = 0; k4 < IN_C / 4; ++k4) {
        float4 xv = xr[k4];               // same addr across the 16 lanes of a node -> broadcast
        int k = k4 * 4;
        acc += xv.x * W[(k + 0) * HID + c];
        acc += xv.y * W[(k + 1) * HID + c];
        acc += xv.z * W[(k + 2) * HID + c];
        acc += xv.w * W[(k + 3) * HID + c];
    }
    a1[(size_t)v * HID + c] = dinv[v] * acc;
}

// Per-edge message + scatter:  acc[d][c] += dinv[d]*(a[s][c] + dinv[s]*e1[c])
// where e1 = edge_attr[e] @ We.  block=256 = 16 edges x 16 channels.
__global__ void scatter_kernel(const int* __restrict__ src, const int* __restrict__ dst,
                               const float* __restrict__ edge_attr,
                               const float* __restrict__ We,
                               const float* __restrict__ a,
                               const float* __restrict__ dinv,
                               float* __restrict__ acc, int E) {
    int t = threadIdx.x;
    int c = t & 15;
    float w[EDGE_C];
#pragma unroll
    for (int k = 0; k < EDGE_C; ++k) w[k] = We[k * HID + c];  // column c of We
    int e = blockIdx.x * 16 + (t >> 4);
    if (e >= E) return;
    int s = src[e];
    int d = dst[e];
    float ea = edge_attr[(size_t)e * EDGE_C + c];
    int lanebase = (t & 63) & ~15;
    float e1 = 0.0f;
#pragma unroll
    for (int k = 0; k < EDGE_C; ++k) {
        float eak = __shfl(ea, lanebase + k, 64);
        e1 += eak * w[k];
    }
    float val = dinv[d] * (a[(size_t)s * HID + c] + dinv[s] * e1);
    atomicAdd(&acc[(size_t)d * HID + c], val);
}

// Epilogue layer 1 fused with layer-2 node transform:
//   h1 = relu(acc1[v] + dinv[v]*a1[v]);  a2[v][c] = dinv[v] * sum_k h1[k]*W2n[k][c]
__global__ void epi1_kernel(const float* __restrict__ acc1, const float* __restrict__ a1,
                            const float* __restrict__ dinv, const float* __restrict__ W2n,
                            float* __restrict__ a2, int n) {
    int t = threadIdx.x;
    int c = t & 15;
    float w[HID];
#pragma unroll
    for (int k = 0; k < HID; ++k) w[k] = W2n[k * HID + c];
    int v = blockIdx.x * 16 + (t >> 4);
    if (v >= n) return;
    float dv = dinv[v];
    float h1 = acc1[(size_t)v * HID + c] + dv * a1[(size_t)v * HID + c];
    h1 = fmaxf(h1, 0.0f);
    int lanebase = (t & 63) & ~15;
    float acc = 0.0f;
#pragma unroll
    for (int k = 0; k < HID; ++k) {
        float h1k = __shfl(h1, lanebase + k, 64);
        acc += h1k * w[k];
    }
    a2[(size_t)v * HID + c] = dv * acc;
}

// Epilogue layer 2 + global mean-pool accumulation
__global__ void epi2_kernel(const float* __restrict__ acc2, const float* __restrict__ a2,
                            const float* __restrict__ dinv, const int* __restrict__ batch,
                            float* __restrict__ pooled, float* __restrict__ cnt, int n) {
    int t = threadIdx.x;
    int c = t & 15;
    int v = blockIdx.x * 16 + (t >> 4);
    if (v >= n) return;
    float dv = dinv[v];
    float h2 = fmaxf(acc2[(size_t)v * HID + c] + dv * a2[(size_t)v * HID + c], 0.0f);
    int g = batch[v];
    atomicAdd(&pooled[g * HID + c], h2);
    if (c == 0) atomicAdd(&cnt[g], 1.0f);
}

// out[g][o] = (pooled[g]/cnt[g]) @ node_W + b   — one block of 512 threads
__global__ void final_kernel(const float* __restrict__ pooled, const float* __restrict__ cnt,
                             const float* __restrict__ W, const float* __restrict__ b,
                             float* __restrict__ out) {
    int t = threadIdx.x;   // 512 = 64 graphs x 8 outputs
    int g = t >> 3;
    int o = t & 7;
    float inv = 1.0f / fmaxf(cnt[g], 1.0f);
    float acc = b[o];
#pragma unroll
    for (int c = 0; c < HID; ++c)
        acc += pooled[g * HID + c] * inv * W[c * OUT_C + o];
    out[g * OUT_C + o] = acc;
}

// ---------------------------------------------------------------------------
extern "C" void kernel_launch(void* const* d_in, const int* in_sizes, int n_in,
                              void* d_out, int out_size, void* d_ws, size_t ws_size,
                              hipStream_t stream) {
    const float* x         = (const float*)d_in[0];
    const int*   edge_idx  = (const int*)d_in[1];
    const float* edge_attr = (const float*)d_in[2];
    const int*   batch     = (const int*)d_in[3];
    const float* W1_node   = (const float*)d_in[4];
    const float* W1_edge   = (const float*)d_in[5];
    const float* W2_node   = (const float*)d_in[6];
    const float* W2_edge   = (const float*)d_in[7];
    const float* node_W    = (const float*)d_in[8];
    const float* node_b    = (const float*)d_in[9];
    float* out = (float*)d_out;

    const int N = in_sizes[0] / IN_C;
    const int E = in_sizes[1] / 2;
    const int* src = edge_idx;
    const int* dst = edge_idx + E;

    // Workspace layout (floats). Zeroed region first (single memset):
    //   acc1[16N] acc2[16N] pooled[16G] cnt[G] deg[N]  | dinv[N] a1[16N] a2[16N]
    float* ws    = (float*)d_ws;
    float* acc1   = ws;
    float* acc2   = acc1 + (size_t)16 * N;
    float* pooled = acc2 + (size_t)16 * N;
    float* cnt    = pooled + 16 * NG;
    float* deg    = cnt + NG;
    float* dinv   = deg + N;
    float* a1     = dinv + N;
    float* a2     = a1 + (size_t)16 * N;

    size_t zero_floats = (size_t)33 * N + 17 * NG;
    hipMemsetAsync(ws, 0, zero_floats * sizeof(float), stream);

    int tb = 256;
    // degrees + dinv
    deg_kernel<<<(E + tb - 1) / tb, tb, 0, stream>>>(dst, deg, E);
    dinv_kernel<<<(N + tb - 1) / tb, tb, 0, stream>>>(deg, dinv, N);
    // layer-1 node transform (scaled)
    xform1_kernel<<<(N + 15) / 16, tb, 0, stream>>>(x, W1_node, dinv, a1, N);
    // layer-1 edge pass
    scatter_kernel<<<(E + 15) / 16, tb, 0, stream>>>(src, dst, edge_attr, W1_edge, a1, dinv, acc1, E);
    // epilogue 1 (relu + layer-2 node transform, h1 never materialized)
    epi1_kernel<<<(N + 15) / 16, tb, 0, stream>>>(acc1, a1, dinv, W2_node, a2, N);
    // layer-2 edge pass
    scatter_kernel<<<(E + 15) / 16, tb, 0, stream>>>(src, dst, edge_attr, W2_edge, a2, dinv, acc2, E);
    // epilogue 2 + pooling
    epi2_kernel<<<(N + 15) / 16, tb, 0, stream>>>(acc2, a2, dinv, batch, pooled, cnt, N);
    // final linear head
    final_kernel<<<1, 512, 0, stream>>>(pooled, cnt, node_W, node_b, out);
}

// Round 2
// 1113.734 us; speedup vs baseline: 1.5434x; 1.5434x over previous
//
#include <hip/hip_runtime.h>
#include <hip/hip_bf16.h>

#define IN_C   128
#define HID    16
#define OUT_C  8
#define EDGE_C 16
#define NG     64

// ---------------------------------------------------------------------------
// Histogram of in-degrees (int atomics; self-loop folded into dinv later)
__global__ void deg_kernel(const int* __restrict__ dst, int* __restrict__ deg, int E) {
    int e = blockIdx.x * blockDim.x + threadIdx.x;
    if (e < E) atomicAdd(&deg[dst[e]], 1);
}

// Exclusive scan, stage A: per-256-block Hillis-Steele
__global__ void scanA_kernel(const int* __restrict__ deg, int* __restrict__ row_tmp,
                             int* __restrict__ blocksum, int n) {
    __shared__ int s[256];
    int t = threadIdx.x;
    int i = blockIdx.x * 256 + t;
    int own = (i < n) ? deg[i] : 0;
    s[t] = own; __syncthreads();
    for (int off = 1; off < 256; off <<= 1) {
        int v = (t >= off) ? s[t - off] : 0;
        __syncthreads();
        s[t] += v;
        __syncthreads();
    }
    if (i < n) row_tmp[i] = s[t] - own;         // exclusive within block
    if (t == 255) blocksum[blockIdx.x] = s[255]; // block total
}

// Stage B: scan the (<=512) block sums in one block
__global__ void scanB_kernel(int* __restrict__ blocksum, int nb) {
    __shared__ int s[512];
    int t = threadIdx.x;
    int own = (t < nb) ? blocksum[t] : 0;
    s[t] = own; __syncthreads();
    for (int off = 1; off < 512; off <<= 1) {
        int v = (t >= off) ? s[t - off] : 0;
        __syncthreads();
        s[t] += v;
        __syncthreads();
    }
    if (t < nb) blocksum[t] = s[t] - own;        // exclusive block offsets
}

// Stage C: row_start = row_tmp + blockoff; init cursor; dinv = rsqrt(deg+1)
__global__ void scanC_kernel(const int* __restrict__ deg, const int* __restrict__ row_tmp,
                             const int* __restrict__ blocksum,
                             int* __restrict__ row_start, int* __restrict__ cursor,
                             float* __restrict__ dinv, int n) {
    int i = blockIdx.x * 256 + threadIdx.x;
    if (i < n) {
        int rs = row_tmp[i] + blocksum[blockIdx.x];
        row_start[i] = rs;
        cursor[i] = rs;
        dinv[i] = rsqrtf((float)deg[i] + 1.0f);
    }
}

// Fill CSR: adj[pos] = (edge_id, src)
__global__ void fill_kernel(const int* __restrict__ src, const int* __restrict__ dst,
                            int* __restrict__ cursor, int2* __restrict__ adj, int E) {
    int e = blockIdx.x * blockDim.x + threadIdx.x;
    if (e < E) {
        int d = dst[e];
        int pos = atomicAdd(&cursor[d], 1);
        adj[pos] = make_int2(e, src[e]);
    }
}

// a1[v][c] = dinv[v] * (x[v] @ W1_node)[c]   (128 -> 16), 16 nodes x 16 ch / block
__global__ void xform1_kernel(const float* __restrict__ x, const float* __restrict__ W,
                              const float* __restrict__ dinv, float* __restrict__ a1, int n) {
    int t = threadIdx.x;
    int v = blockIdx.x * 16 + (t >> 4);
    int c = t & 15;
    if (v >= n) return;
    const float4* xr = (const float4*)(x + (size_t)v * IN_C);
    float acc = 0.0f;
#pragma unroll
    for (int k4 = 0; k4 < IN_C / 4; ++k4) {
        float4 xv = xr[k4];
        int k = k4 * 4;
        acc += xv.x * W[(k + 0) * HID + c];
        acc += xv.y * W[(k + 1) * HID + c];
        acc += xv.z * W[(k + 2) * HID + c];
        acc += xv.w * W[(k + 3) * HID + c];
    }
    a1[(size_t)v * HID + c] = dinv[v] * acc;
}

// CSR gather conv: per 16-lane group, one destination node; accumulate in regs.
//   pre = dinv[v] * (sum_edges(a_in[s] + dinv[s]*(ea@We)) + a_in[v]);  h = relu(pre)
// FUSE: out = dinv[v] * (h @ Wn)   else: out = h
template<bool FUSE>
__global__ void gather_kernel(const int2* __restrict__ adj,
                              const int* __restrict__ row_start,
                              const int* __restrict__ deg,
                              const float* __restrict__ edge_attr,
                              const float* __restrict__ We,   // EDGE_C x HID
                              const float* __restrict__ Wn,   // HID x HID (FUSE only)
                              const float* __restrict__ a_in,
                              const float* __restrict__ dinv,
                              float* __restrict__ out, int n) {
    int t = threadIdx.x;
    int c = t & 15;
    float we[EDGE_C];
#pragma unroll
    for (int k = 0; k < EDGE_C; ++k) we[k] = We[k * HID + c];
    float wn[HID];
    if constexpr (FUSE) {
#pragma unroll
        for (int k = 0; k < HID; ++k) wn[k] = Wn[k * HID + c];
    }
    int v = blockIdx.x * 16 + (t >> 4);
    if (v >= n) return;
    int start = row_start[v];
    int dg = deg[v];
    int lanebase = (t & 63) & ~15;
    float acc = 0.0f;
    int2 ad = (dg > 0) ? adj[start] : make_int2(0, 0);
    for (int i = 0; i < dg; ++i) {
        int e = ad.x, s = ad.y;
        float ea = edge_attr[(size_t)e * EDGE_C + c];
        float ds = dinv[s];
        float av = a_in[(size_t)s * HID + c];
        if (i + 1 < dg) ad = adj[start + i + 1];   // 1-deep prefetch
        float e1 = 0.0f;
#pragma unroll
        for (int k = 0; k < EDGE_C; ++k) {
            float eak = __shfl(ea, lanebase + k, 64);
            e1 += eak * we[k];
        }
        acc += av + ds * e1;
    }
    float dv = dinv[v];
    float pre = dv * (acc + a_in[(size_t)v * HID + c]);
    float h = fmaxf(pre, 0.0f);
    if constexpr (FUSE) {
        float o = 0.0f;
#pragma unroll
        for (int k = 0; k < HID; ++k) {
            float hk = __shfl(h, lanebase + k, 64);
            o += hk * wn[k];
        }
        out[(size_t)v * HID + c] = dv * o;
    } else {
        out[(size_t)v * HID + c] = h;
    }
}

// One block per graph: binary-search the sorted batch index for [start,end),
// reduce h2 over that node range in LDS, fused 16x8 head. No atomics.
__global__ void pool_final_kernel(const float* __restrict__ h2,
                                  const int* __restrict__ batch,
                                  const float* __restrict__ W, const float* __restrict__ b,
                                  float* __restrict__ out, int n) {
    __shared__ float sdata[256];
    int g = blockIdx.x;
    int t = threadIdx.x;
    int c = t & 15;
    int lo = 0, hi = n;
    while (lo < hi) { int m = (lo + hi) >> 1; if (batch[m] < g) lo = m + 1; else hi = m; }
    int start = lo;
    hi = n;
    while (lo < hi) { int m = (lo + hi) >> 1; if (batch[m] < g + 1) lo = m + 1; else hi = m; }
    int end = lo;
    float acc = 0.0f;
    for (int v = start + (t >> 4); v < end; v += 16)
        acc += h2[(size_t)v * HID + c];
    sdata[t] = acc; __syncthreads();
    for (int s = 128; s >= 16; s >>= 1) {
        if (t < s) sdata[t] += sdata[t + s];
        __syncthreads();
    }
    if (t < OUT_C) {
        float inv = 1.0f / fmaxf((float)(end - start), 1.0f);
        float o = b[t];
#pragma unroll
        for (int cc = 0; cc < HID; ++cc)
            o += sdata[cc] * inv * W[cc * OUT_C + t];
        out[g * OUT_C + t] = o;
    }
}

// ---------------------------------------------------------------------------
extern "C" void kernel_launch(void* const* d_in, const int* in_sizes, int n_in,
                              void* d_out, int out_size, void* d_ws, size_t ws_size,
                              hipStream_t stream) {
    const float* x         = (const float*)d_in[0];
    const int*   edge_idx  = (const int*)d_in[1];
    const float* edge_attr = (const float*)d_in[2];
    const int*   batch     = (const int*)d_in[3];
    const float* W1_node   = (const float*)d_in[4];
    const float* W1_edge   = (const float*)d_in[5];
    const float* W2_node   = (const float*)d_in[6];
    const float* W2_edge   = (const float*)d_in[7];
    const float* node_W    = (const float*)d_in[8];
    const float* node_b    = (const float*)d_in[9];
    float* out = (float*)d_out;

    const int N = in_sizes[0] / IN_C;
    const int E = in_sizes[1] / 2;
    const int* src = edge_idx;
    const int* dst = edge_idx + E;

    // Workspace layout (adj first for 8B alignment):
    char* p = (char*)d_ws;
    int2*  adj       = (int2*)p;          p += sizeof(int2) * (size_t)E;
    int*   deg       = (int*)p;           p += sizeof(int) * (size_t)N;   // zeroed
    int*   row_tmp   = (int*)p;           p += sizeof(int) * (size_t)N;
    int*   row_start = (int*)p;           p += sizeof(int) * (size_t)N;
    int*   cursor    = (int*)p;           p += sizeof(int) * (size_t)N;
    int*   blocksum  = (int*)p;           p += sizeof(int) * 512;
    float* dinv      = (float*)p;         p += sizeof(float) * (size_t)N;
    float* a1        = (float*)p;         p += sizeof(float) * (size_t)16 * N;
    float* a2        = (float*)p;         p += sizeof(float) * (size_t)16 * N;
    float* h2        = a1;                // a1 dead after layer-1 gather

    hipMemsetAsync(deg, 0, sizeof(int) * (size_t)N, stream);

    const int tb = 256;
    const int nbN = (N + 255) / 256;          // 391 <= 512
    deg_kernel <<<(E + tb - 1) / tb, tb, 0, stream>>>(dst, deg, E);
    scanA_kernel<<<nbN, 256, 0, stream>>>(deg, row_tmp, blocksum, N);
    scanB_kernel<<<1, 512, 0, stream>>>(blocksum, nbN);
    scanC_kernel<<<nbN, 256, 0, stream>>>(deg, row_tmp, blocksum, row_start, cursor, dinv, N);
    fill_kernel <<<(E + tb - 1) / tb, tb, 0, stream>>>(src, dst, cursor, adj, E);

    xform1_kernel<<<(N + 15) / 16, tb, 0, stream>>>(x, W1_node, dinv, a1, N);

    gather_kernel<true ><<<(N + 15) / 16, tb, 0, stream>>>(
        adj, row_start, deg, edge_attr, W1_edge, W2_node, a1, dinv, a2, N);
    gather_kernel<false><<<(N + 15) / 16, tb, 0, stream>>>(
        adj, row_start, deg, edge_attr, W2_edge, nullptr, a2, dinv, h2, N);

    pool_final_kernel<<<NG, 256, 0, stream>>>(h2, batch, node_W, node_b, out, N);
}

// Round 3
// 920.343 us; speedup vs baseline: 1.8677x; 1.2101x over previous
//
#include <hip/hip_runtime.h>
#include <hip/hip_bf16.h>

#define IN_C   128
#define HID    16
#define OUT_C  8
#define EDGE_C 16
#define NG     64
#define NRANGE 8   // dst ranges, pinned to XCDs via blockIdx % 8

// ---------------------------------------------------------------------------
__global__ void deg_kernel(const int* __restrict__ dst, int* __restrict__ deg, int E) {
    int e = blockIdx.x * blockDim.x + threadIdx.x;
    if (e < E) atomicAdd(&deg[dst[e]], 1);
}

// Exclusive scan stage A: per-256-block Hillis-Steele (writes exclusive-within-block)
__global__ void scanA_kernel(const int* __restrict__ deg, int* __restrict__ row_start,
                             int* __restrict__ blocksum, int n) {
    __shared__ int s[256];
    int t = threadIdx.x;
    int i = blockIdx.x * 256 + t;
    int own = (i < n) ? deg[i] : 0;
    s[t] = own; __syncthreads();
    for (int off = 1; off < 256; off <<= 1) {
        int v = (t >= off) ? s[t - off] : 0;
        __syncthreads();
        s[t] += v;
        __syncthreads();
    }
    if (i < n) row_start[i] = s[t] - own;
    if (t == 255) blocksum[blockIdx.x] = s[255];
}

__global__ void scanB_kernel(int* __restrict__ blocksum, int nb) {
    __shared__ int s[512];
    int t = threadIdx.x;
    int own = (t < nb) ? blocksum[t] : 0;
    s[t] = own; __syncthreads();
    for (int off = 1; off < 512; off <<= 1) {
        int v = (t >= off) ? s[t - off] : 0;
        __syncthreads();
        s[t] += v;
        __syncthreads();
    }
    if (t < nb) blocksum[t] = s[t] - own;
}

// row_start += blockoff (in place); cursor = row_start; dinv = rsqrt(deg+1)
__global__ void scanC_kernel(const int* __restrict__ deg, int* __restrict__ row_start,
                             const int* __restrict__ blocksum,
                             int* __restrict__ cursor, float* __restrict__ dinv, int n) {
    int i = blockIdx.x * 256 + threadIdx.x;
    if (i < n) {
        int rs = row_start[i] + blocksum[blockIdx.x];
        row_start[i] = rs;
        cursor[i] = rs;
        dinv[i] = rsqrtf((float)deg[i] + 1.0f);
    }
}

// XCD-pinned CSR fill: range r = blockIdx%8 owns dst in [r*rs, r*rs+rs).
// Blocks with the same r partition the edge list; every edge is written by
// exactly one (r,q). Writes for one dst stay in one XCD's L2 -> dense writebacks.
__global__ void fill_kernel(const int* __restrict__ src, const int* __restrict__ dst,
                            int* __restrict__ cursor, int2* __restrict__ adj,
                            int E, int range_size, int bpr) {
    int r = blockIdx.x & (NRANGE - 1);
    int q = blockIdx.x >> 3;
    int lo = r * range_size;
    int hi = lo + range_size;
    long long chunk = ((long long)E + bpr - 1) / bpr;
    int e0 = (int)((long long)q * chunk);
    long long e1l = (long long)e0 + chunk;
    int e1 = (e1l < E) ? (int)e1l : E;
    for (int e = e0 + threadIdx.x; e < e1; e += blockDim.x) {
        int d = dst[e];
        if (d >= lo && d < hi) {
            int pos = atomicAdd(&cursor[d], 1);
            adj[pos] = make_int2(e, src[e]);
        }
    }
}

// a1[v][c] = dinv[v] * (x[v] @ W1_node)[c]
__global__ void xform1_kernel(const float* __restrict__ x, const float* __restrict__ W,
                              const float* __restrict__ dinv, float* __restrict__ a1, int n) {
    int t = threadIdx.x;
    int v = blockIdx.x * 16 + (t >> 4);
    int c = t & 15;
    if (v >= n) return;
    const float4* xr = (const float4*)(x + (size_t)v * IN_C);
    float acc = 0.0f;
#pragma unroll
    for (int k4 = 0; k4 < IN_C / 4; ++k4) {
        float4 xv = xr[k4];
        int k = k4 * 4;
        acc += xv.x * W[(k + 0) * HID + c];
        acc += xv.y * W[(k + 1) * HID + c];
        acc += xv.z * W[(k + 2) * HID + c];
        acc += xv.w * W[(k + 3) * HID + c];
    }
    a1[(size_t)v * HID + c] = dinv[v] * acc;
}

// Pass 1: wave per node, 4 edge-slots x 16 channels.
//   ES[v][c] = sum_e dinv[s]*ea[e][c]   (layer-independent, stored for pass 2)
//   S1[v][c] = sum_e a1[s][c]
//   pre1 = dinv[v]*(S1 + a1[v] + ES@W1e); h1 = relu(pre1)
//   a2[v] = dinv[v]*(h1 @ W2n)
__global__ void gather1_kernel(const int2* __restrict__ adj, const int* __restrict__ row_start,
                               const int* __restrict__ deg,
                               const float* __restrict__ edge_attr,
                               const float* __restrict__ W1e, const float* __restrict__ W2n,
                               const float* __restrict__ a1, const float* __restrict__ dinv,
                               float* __restrict__ a2, float* __restrict__ ES, int n) {
    int t = threadIdx.x;
    int lane = t & 63;
    int slot = lane >> 4;
    int c = lane & 15;
    float we[EDGE_C], wn[HID];
#pragma unroll
    for (int k = 0; k < EDGE_C; ++k) we[k] = W1e[k * HID + c];
#pragma unroll
    for (int k = 0; k < HID; ++k) wn[k] = W2n[k * HID + c];
    int v = blockIdx.x * 4 + (t >> 6);          // wave-uniform
    if (v >= n) return;
    int start = row_start[v];
    int dg = deg[v];
    float es = 0.0f, s1 = 0.0f;
    for (int i = slot; i < dg; i += 4) {
        int2 ad = adj[start + i];
        float ea = edge_attr[(size_t)ad.x * EDGE_C + c];   // coalesced 64B row per slot
        float ds = dinv[ad.y];
        float av = a1[(size_t)ad.y * HID + c];
        es += ds * ea;
        s1 += av;
    }
    es += __shfl_xor(es, 16, 64); es += __shfl_xor(es, 32, 64);
    s1 += __shfl_xor(s1, 16, 64); s1 += __shfl_xor(s1, 32, 64);
    float dv = dinv[v];
    int lanebase = lane & ~15;
    float e1 = 0.0f;
#pragma unroll
    for (int k = 0; k < EDGE_C; ++k)
        e1 += __shfl(es, lanebase + k, 64) * we[k];
    float h = fmaxf(dv * (s1 + a1[(size_t)v * HID + c] + e1), 0.0f);
    float o = 0.0f;
#pragma unroll
    for (int k = 0; k < HID; ++k)
        o += __shfl(h, lanebase + k, 64) * wn[k];
    if (slot == 0) {
        a2[(size_t)v * HID + c] = dv * o;
        ES[(size_t)v * HID + c] = es;
    }
}

// Pass 2: neighbor-sum of a2 only (no edge_attr!), then
//   h2 = relu(dinv[v]*(S2 + a2[v] + ES@W2e))
__global__ void gather2_kernel(const int2* __restrict__ adj, const int* __restrict__ row_start,
                               const int* __restrict__ deg,
                               const float* __restrict__ W2e,
                               const float* __restrict__ a2, const float* __restrict__ dinv,
                               const float* __restrict__ ES, float* __restrict__ h2, int n) {
    int t = threadIdx.x;
    int lane = t & 63;
    int slot = lane >> 4;
    int c = lane & 15;
    float we[EDGE_C];
#pragma unroll
    for (int k = 0; k < EDGE_C; ++k) we[k] = W2e[k * HID + c];
    int v = blockIdx.x * 4 + (t >> 6);
    if (v >= n) return;
    int start = row_start[v];
    int dg = deg[v];
    float s2 = 0.0f;
    for (int i = slot; i < dg; i += 4) {
        int2 ad = adj[start + i];
        s2 += a2[(size_t)ad.y * HID + c];
    }
    s2 += __shfl_xor(s2, 16, 64); s2 += __shfl_xor(s2, 32, 64);
    float dv = dinv[v];
    int lanebase = lane & ~15;
    float esv = ES[(size_t)v * HID + c];
    float e2 = 0.0f;
#pragma unroll
    for (int k = 0; k < EDGE_C; ++k)
        e2 += __shfl(esv, lanebase + k, 64) * we[k];
    float h = fmaxf(dv * (s2 + a2[(size_t)v * HID + c] + e2), 0.0f);
    if (slot == 0) h2[(size_t)v * HID + c] = h;
}

// One block per graph: binary-search sorted batch for [start,end), LDS-reduce, 16x8 head.
__global__ void pool_final_kernel(const float* __restrict__ h2,
                                  const int* __restrict__ batch,
                                  const float* __restrict__ W, const float* __restrict__ b,
                                  float* __restrict__ out, int n) {
    __shared__ float sdata[256];
    int g = blockIdx.x;
    int t = threadIdx.x;
    int c = t & 15;
    int lo = 0, hi = n;
    while (lo < hi) { int m = (lo + hi) >> 1; if (batch[m] < g) lo = m + 1; else hi = m; }
    int start = lo;
    hi = n;
    while (lo < hi) { int m = (lo + hi) >> 1; if (batch[m] < g + 1) lo = m + 1; else hi = m; }
    int end = lo;
    float acc = 0.0f;
    for (int v = start + (t >> 4); v < end; v += 16)
        acc += h2[(size_t)v * HID + c];
    sdata[t] = acc; __syncthreads();
    for (int s = 128; s >= 16; s >>= 1) {
        if (t < s) sdata[t] += sdata[t + s];
        __syncthreads();
    }
    if (t < OUT_C) {
        float inv = 1.0f / fmaxf((float)(end - start), 1.0f);
        float o = b[t];
#pragma unroll
        for (int cc = 0; cc < HID; ++cc)
            o += sdata[cc] * inv * W[cc * OUT_C + t];
        out[g * OUT_C + t] = o;
    }
}

// ---------------------------------------------------------------------------
extern "C" void kernel_launch(void* const* d_in, const int* in_sizes, int n_in,
                              void* d_out, int out_size, void* d_ws, size_t ws_size,
                              hipStream_t stream) {
    const float* x         = (const float*)d_in[0];
    const int*   edge_idx  = (const int*)d_in[1];
    const float* edge_attr = (const float*)d_in[2];
    const int*   batch     = (const int*)d_in[3];
    const float* W1_node   = (const float*)d_in[4];
    const float* W1_edge   = (const float*)d_in[5];
    const float* W2_node   = (const float*)d_in[6];
    const float* W2_edge   = (const float*)d_in[7];
    const float* node_W    = (const float*)d_in[8];
    const float* node_b    = (const float*)d_in[9];
    float* out = (float*)d_out;

    const int N = in_sizes[0] / IN_C;
    const int E = in_sizes[1] / 2;
    const int* src = edge_idx;
    const int* dst = edge_idx + E;

    // Workspace layout (adj first for 8B alignment):
    char* p = (char*)d_ws;
    int2*  adj       = (int2*)p;   p += sizeof(int2) * (size_t)E;
    int*   deg       = (int*)p;    p += sizeof(int) * (size_t)N;   // zeroed
    int*   row_start = (int*)p;    p += sizeof(int) * (size_t)N;
    int*   cursor    = (int*)p;    p += sizeof(int) * (size_t)N;
    int*   blocksum  = (int*)p;    p += sizeof(int) * 512;
    float* dinv      = (float*)p;  p += sizeof(float) * (size_t)N;
    float* a1        = (float*)p;  p += sizeof(float) * (size_t)HID * N;
    float* a2        = (float*)p;  p += sizeof(float) * (size_t)HID * N;
    float* ES        = (float*)p;  p += sizeof(float) * (size_t)HID * N;
    float* h2        = a1;         // a1 dead after gather1

    hipMemsetAsync(deg, 0, sizeof(int) * (size_t)N, stream);

    const int tb = 256;
    const int nbN = (N + 255) / 256;
    deg_kernel <<<(E + tb - 1) / tb, tb, 0, stream>>>(dst, deg, E);
    scanA_kernel<<<nbN, 256, 0, stream>>>(deg, row_start, blocksum, N);
    scanB_kernel<<<1, 512, 0, stream>>>(blocksum, nbN);
    scanC_kernel<<<nbN, 256, 0, stream>>>(deg, row_start, blocksum, cursor, dinv, N);

    const int range_size = (N + NRANGE - 1) / NRANGE;
    const int bpr = 128;                       // blocks per range -> 1024 blocks total
    fill_kernel<<<NRANGE * bpr, tb, 0, stream>>>(src, dst, cursor, adj, E, range_size, bpr);

    xform1_kernel<<<(N + 15) / 16, tb, 0, stream>>>(x, W1_node, dinv, a1, N);

    gather1_kernel<<<(N + 3) / 4, tb, 0, stream>>>(
        adj, row_start, deg, edge_attr, W1_edge, W2_node, a1, dinv, a2, ES, N);
    gather2_kernel<<<(N + 3) / 4, tb, 0, stream>>>(
        adj, row_start, deg, W2_edge, a2, dinv, ES, h2, N);

    pool_final_kernel<<<NG, 256, 0, stream>>>(h2, batch, node_W, node_b, out, N);
}